// Round 4
// baseline (778.624 us; speedup 1.0000x reference)
//
#include <hip/hip_runtime.h>
#include <hip/hip_bf16.h>
#include <math.h>

#define B_  32
#define T_  2048
#define D_  512
#define V_  1024
#define K_  3

typedef __attribute__((ext_vector_type(8))) short   short8;
typedef __attribute__((ext_vector_type(4))) float   floatx4;

#define SCALE_A 64.0f          // activation fp8 scale (conv2 input)
#define SCALE_W 16.0f          // weight fp8 scale
#define INV_SCALES (1.0f/(SCALE_A*SCALE_W))

// ---- output flat offsets (elements, fp32) ----
#define OFF0 0        // global_rate      [32]
#define OFF1 32       // summary_state    [32*512]
#define OFF2 16416    // residual_mean    [32]
#define OFF3 16448    // residual_var     [32]
#define OFF4 16480    // coverage         [32]
#define OFF5 16512    // mask             [32*2048]
#define OFF6 82048    // logdur           [32*2048]
#define OFF7 147584   // ref_residual     [32*2048]
#define OFF8 213120   // attn             [32*2048]
#define OFF9 278656   // prompt_role_fit  [32*2048]
#define OFF10 344192  // coeff_norm       [32]

// ---- workspace byte offsets (total 2,752,640 B = 2.63 MB) ----
#define WS_RR     0          // fp32 [32][2048]              262144 B
#define WS_SUP    262144     // fp32 [32]                       128 B
#define WS_PSUM   262272     // fp32 [32][512]                65536 B
#define WS_PSUMSQ 327808     // fp32 [32][512]                65536 B
#define WS_W1P    393344     // bf16 frag-packed conv1 w    1572864 B
#define WS_W2P    1966208    // fp8  frag-packed conv2 w     786432 B

__device__ __forceinline__ __hip_bfloat16 f2bf(float x) { return __float2bfloat16(x); }
__device__ __forceinline__ float gelu_exact(float v) {
    return 0.5f * v * (1.0f + erff(v * 0.70710678118654752440f));
}
__device__ __forceinline__ unsigned char f2fp8(float x) {
    int v = __builtin_amdgcn_cvt_pk_fp8_f32(x, x, 0, false);
    return (unsigned char)(v & 0xFF);
}
__device__ __forceinline__ float clampf(float v, float lo, float hi) {
    v = (v > lo) ? v : lo;
    return (v < hi) ? v : hi;
}

__device__ __forceinline__ float block_reduce_sum(float v, float* red, int tid) {
    __syncthreads();
    red[tid] = v;
    __syncthreads();
    for (int s = 128; s > 0; s >>= 1) {
        if (tid < s) red[tid] += red[tid + s];
        __syncthreads();
    }
    float r = red[0];
    __syncthreads();
    return r;
}

// ---------------------------------------------------------------------------
// Kernel 1: prepack weights into MFMA-fragment-linear layouts.
//  W1p bf16: idx = (((k*16+ci)*32+ntg)*64+lane)*8+e  = w1[col][kin][k] where
//    col = ntg*16 + (lane&15), kin = ci*32 + (lane>>4)*8 + e
//  W2p fp8 (*16): same layout for conv2.  Also zero psum/psumsq (32768 f).
// ---------------------------------------------------------------------------
__global__ __launch_bounds__(256) void prepack_kernel(
    const float* __restrict__ w1, const float* __restrict__ w2,
    __hip_bfloat16* __restrict__ W1p, unsigned char* __restrict__ W2p,
    float* __restrict__ psum)
{
    int pid = blockIdx.x * 256 + threadIdx.x;   // 0 .. 98303
    int lane = pid & 63;
    int n = lane & 15, q = lane >> 4;
    int ntg = (pid >> 6) & 31;
    int ci  = (pid >> 11) & 15;
    int k   = pid >> 15;                        // 0..2
    int col = ntg * 16 + n;
    int kin = ci * 32 + q * 8;

    short8 wv1;
    unsigned char wv2[8];
    #pragma unroll
    for (int e = 0; e < 8; ++e) {
        size_t src = ((size_t)col * D_ + kin + e) * K_ + k;
        union { __hip_bfloat16 b; short s; } u;
        u.b = f2bf(w1[src]);
        wv1[e] = u.s;
        wv2[e] = f2fp8(w2[src] * SCALE_W);
    }
    *(short8*)(W1p + (size_t)pid * 8) = wv1;
    *(double*)(W2p + (size_t)pid * 8) = *(double*)wv2;

    if (pid < 32768) psum[pid] = 0.0f;          // psum + psumsq contiguous
}

// ---------------------------------------------------------------------------
// Kernel 2: per-batch stats (median via LDS bitonic sort) + T-wise outputs
// ---------------------------------------------------------------------------
__global__ __launch_bounds__(256) void stats_kernel(
    const float* __restrict__ dur, const float* __restrict__ maskp,
    float* __restrict__ rr_ws, float* __restrict__ sup_ws,
    float* __restrict__ out)
{
    int b = blockIdx.x;
    int tid = threadIdx.x;
    __shared__ float sv[T_];
    __shared__ float red[256];
    __shared__ float nsh;

    const float* durb = dur + (size_t)b * T_;
    const float* mkb  = maskp + (size_t)b * T_;

    float ld[8], mk[8];
    float cnt = 0.0f;
    #pragma unroll
    for (int i = 0; i < 8; ++i) {
        int t = tid + i * 256;
        float m = clampf(mkb[t], 0.0f, 1.0f);
        float dv = durb[t];
        dv = (dv >= 1e-4f) ? dv : 1e-4f;         // NaN-safe clamp
        float l = logf(dv) * m;
        ld[i] = l; mk[i] = m;
        bool valid = m > 0.5f;
        cnt += valid ? 1.0f : 0.0f;
        sv[t] = valid ? l : 1e30f;
    }
    float n = block_reduce_sum(cnt, red, tid);
    if (tid == 0) nsh = n;

    // bitonic sort ascending (invalid = 1e30 -> tail)
    for (int k = 2; k <= T_; k <<= 1) {
        for (int j = k >> 1; j > 0; j >>= 1) {
            __syncthreads();
            #pragma unroll
            for (int s = 0; s < 8; ++s) {
                int i = tid + s * 256;
                int ixj = i ^ j;
                if (ixj > i) {
                    float a = sv[i], c = sv[ixj];
                    bool up = ((i & k) == 0);
                    if ((a > c) == up) { sv[i] = c; sv[ixj] = a; }
                }
            }
        }
    }
    __syncthreads();
    n = nsh;
    float med = 0.0f;
    if (n > 0.5f) {
        int ni = (int)(n + 0.5f);
        med = sv[(ni - 1) >> 1];    // torch-style lower median
    }
    med = clampf(med, -20.0f, 20.0f);            // valid range; NaN-proof output

    float denom = (n > 1.0f) ? n : 1.0f;
    float rv[8];
    float ssum = 0.0f;
    #pragma unroll
    for (int i = 0; i < 8; ++i) { rv[i] = (ld[i] - med) * mk[i]; ssum += rv[i]; }
    float rsum = block_reduce_sum(ssum, red, tid);
    float rm = clampf(rsum / denom, -40.0f, 40.0f);

    float vsum_l = 0.0f;
    #pragma unroll
    for (int i = 0; i < 8; ++i) { float dd = rv[i] - rm; vsum_l += dd * dd * mk[i]; }
    float vsum = block_reduce_sum(vsum_l, red, tid);
    float var = clampf(vsum / denom, 1e-4f, 1e4f);

    float inv_sup = 1.0f / denom;
    #pragma unroll
    for (int i = 0; i < 8; ++i) {
        int t = tid + i * 256;
        size_t o = (size_t)b * T_ + t;
        out[OFF5 + o] = mk[i];
        out[OFF6 + o] = ld[i];
        out[OFF7 + o] = rv[i];
        out[OFF8 + o] = mk[i] * inv_sup;
        out[OFF9 + o] = rm * mk[i];
        rr_ws[o] = rv[i];
    }
    if (tid == 0) {
        out[OFF0 + b] = med;
        out[OFF2 + b] = rm;
        out[OFF3 + b] = var;
        float cov = n * (1.0f / (float)T_);
        out[OFF4 + b] = (cov > 0.05f) ? cov : 0.05f;
        sup_ws[b] = n;
    }
}

// ---------------------------------------------------------------------------
// Kernel 3: FUSED conv1 -> gelu -> conv2 -> gelu -> LN -> masked column sums.
//   BM=64 output rows x full 512 cols per block. Weights streamed from
//   fragment-packed global (no weight LDS). Static LDS = 49.6 KB.
// ---------------------------------------------------------------------------
#define NR0 84          // H0 rows staged (64 + halos + tile slack)
#define C1T 5           // conv1 M-tiles (80 rows computed, 66 stored)
#define H1R 68          // H1 rows stored (64 + 2 halo + pad)
#define H1S 520         // H1 row stride bytes (512 + 8)

__global__ __launch_bounds__(256, 1) void fused_conv_kernel(
    const int* __restrict__ ids, const float* __restrict__ rr,
    const float* __restrict__ emb,
    const float* __restrict__ aux_w, const float* __restrict__ aux_b,
    const __hip_bfloat16* __restrict__ W1p, const float* __restrict__ bias1,
    const unsigned char* __restrict__ W2p, const float* __restrict__ bias2,
    const float* __restrict__ ln_g, const float* __restrict__ ln_b,
    const float* __restrict__ maskp,
    float* __restrict__ psum, float* __restrict__ psumsq)
{
    __shared__ int   lid[NR0];
    __shared__ float lrr[NR0];
    __shared__ __align__(16) __hip_bfloat16 H0[NR0 * 40];   // 6720 B
    __shared__ __align__(16) unsigned char H1[H1R * H1S];   // 35360 B
    __shared__ float mrow[64];
    __shared__ float part[64][4][2];
    __shared__ float tot[64][2];
    __shared__ float colsum[512][2];

    int tile = blockIdx.x;          // 0..31
    int b    = blockIdx.y;          // 0..31
    int r0   = tile << 6;           // output rows r0..r0+63
    int tid  = threadIdx.x;
    int wave = tid >> 6, lane = tid & 63;
    int q = lane >> 4, m16 = lane & 15;
    int nbase = wave << 7;          // 128-col slice per wave

    if (tid < NR0) {
        int t = r0 - 4 + tid;       // H0 row i <-> global t = r0-4+i
        bool v = (t >= 0) && (t < T_);
        lid[tid] = v ? ids[b * T_ + t] : -1;
        lrr[tid] = v ? rr[(size_t)b * T_ + t] : 0.0f;
    }
    if (tid < 64)
        mrow[tid] = clampf(maskp[(size_t)b * T_ + r0 + tid], 0.0f, 1.0f);

    // ================= phase 1: conv1 (bf16 MFMA, frag-packed weights) ======
    floatx4 acc1[C1T][8];
    #pragma unroll
    for (int i = 0; i < C1T; ++i)
        #pragma unroll
        for (int j = 0; j < 8; ++j)
            acc1[i][j] = (floatx4){0.f, 0.f, 0.f, 0.f};

    for (int ci = 0; ci < 16; ++ci) {
        __syncthreads();            // protect H0 from previous readers
        // stage H0: 84 rows x 32 cols (fp32 gather -> bf16)
        for (int g = tid; g < NR0 * 8; g += 256) {
            int row = g >> 3, c4 = g & 7;
            int id = lid[row];
            float vr = lrr[row];
            float zf = (id < 0) ? 0.0f : 1.0f;
            int idc = (id < 0) ? 0 : id;
            float4 ev = *(const float4*)(emb + (size_t)idc * D_ + ci * 32 + c4 * 4);
            float4 aw = *(const float4*)(aux_w + ci * 32 + c4 * 4);
            float4 ab = *(const float4*)(aux_b + ci * 32 + c4 * 4);
            short hv[4];
            union { __hip_bfloat16 b; short s; } u;
            u.b = f2bf((ev.x + vr * aw.x + ab.x) * zf); hv[0] = u.s;
            u.b = f2bf((ev.y + vr * aw.y + ab.y) * zf); hv[1] = u.s;
            u.b = f2bf((ev.z + vr * aw.z + ab.z) * zf); hv[2] = u.s;
            u.b = f2bf((ev.w + vr * aw.w + ab.w) * zf); hv[3] = u.s;
            *(double*)(&H0[row * 40 + c4 * 4]) = *(double*)hv;
        }
        __syncthreads();            // H0 ready
        #pragma unroll
        for (int k1 = 0; k1 < 3; ++k1) {
            short8 bfr[8];
            #pragma unroll
            for (int nt = 0; nt < 8; ++nt) {
                int ntg = wave * 8 + nt;
                bfr[nt] = *(const short8*)(W1p +
                    ((size_t)((k1 * 16 + ci) * 32 + ntg) * 64 + lane) * 8);
            }
            #pragma unroll
            for (int mt = 0; mt < C1T; ++mt) {
                short8 afr = *(const short8*)(&H0[(mt * 16 + m16 + k1) * 40 + q * 8]);
                #pragma unroll
                for (int nt = 0; nt < 8; ++nt)
                    acc1[mt][nt] = __builtin_amdgcn_mfma_f32_16x16x32_bf16(
                        afr, bfr[nt], acc1[mt][nt], 0, 0, 0);
            }
        }
    }
    __syncthreads();                // last H0 reads done; H1 region reuse safe

    // phase-1 epilogue: gelu(acc+bias1)*SCALE_A -> fp8 H1 rows 0..65
    //   H1 row j <-> conv1 global t1 = r0-2+j ; t1<0 rows forced to 0.
    #pragma unroll
    for (int mt = 0; mt < C1T; ++mt) {
        #pragma unroll
        for (int nt = 0; nt < 8; ++nt) {
            int col = nbase + nt * 16 + m16;
            float bsv = bias1[col];
            #pragma unroll
            for (int r = 0; r < 4; ++r) {
                int j = mt * 16 + q * 4 + r;
                if (j < 66) {
                    float val = gelu_exact(acc1[mt][nt][r] + bsv) * SCALE_A;
                    if (r0 - 2 + j < 0) val = 0.0f;
                    H1[j * H1S + col] = f2fp8(val);
                }
            }
        }
    }
    __syncthreads();                // H1 complete

    // ================= phase 2: conv2 (fp8 MFMA, frag-packed weights) =======
    floatx4 acc2[4][8];
    #pragma unroll
    for (int i = 0; i < 4; ++i)
        #pragma unroll
        for (int j = 0; j < 8; ++j)
            acc2[i][j] = (floatx4){0.f, 0.f, 0.f, 0.f};

    for (int s = 0; s < 48; ++s) {
        int k2 = s >> 4, ci = s & 15;
        long bfr2[8];
        #pragma unroll
        for (int nt = 0; nt < 8; ++nt) {
            int ntg = wave * 8 + nt;
            bfr2[nt] = *(const long*)(W2p +
                ((size_t)((k2 * 16 + ci) * 32 + ntg) * 64 + lane) * 8);
        }
        #pragma unroll
        for (int mt = 0; mt < 4; ++mt) {
            long afr2 = *(const long*)(&H1[(mt * 16 + m16 + k2) * H1S + ci * 32 + q * 8]);
            #pragma unroll
            for (int nt = 0; nt < 8; ++nt)
                acc2[mt][nt] = __builtin_amdgcn_mfma_f32_16x16x32_fp8_fp8(
                    afr2, bfr2[nt], acc2[mt][nt], 0, 0, 0);
        }
    }

    // ================= phase 3: gelu + LN + masked column sums ==============
    #pragma unroll
    for (int mt = 0; mt < 4; ++mt)
        #pragma unroll
        for (int nt = 0; nt < 8; ++nt) {
            int col = nbase + nt * 16 + m16;
            float bsv = bias2[col];
            #pragma unroll
            for (int r = 0; r < 4; ++r)
                acc2[mt][nt][r] = gelu_exact(acc2[mt][nt][r] * INV_SCALES + bsv);
        }

    // row sums over 512 cols: 8 local cols -> xor over 16 col-lanes -> 4 waves
    #pragma unroll
    for (int mt = 0; mt < 4; ++mt) {
        #pragma unroll
        for (int r = 0; r < 4; ++r) {
            float rs = 0.f, rq = 0.f;
            #pragma unroll
            for (int nt = 0; nt < 8; ++nt) {
                float v = acc2[mt][nt][r];
                rs += v; rq += v * v;
            }
            rs += __shfl_xor(rs, 1);  rq += __shfl_xor(rq, 1);
            rs += __shfl_xor(rs, 2);  rq += __shfl_xor(rq, 2);
            rs += __shfl_xor(rs, 4);  rq += __shfl_xor(rq, 4);
            rs += __shfl_xor(rs, 8);  rq += __shfl_xor(rq, 8);
            if (m16 == 0) {
                int row = mt * 16 + q * 4 + r;
                part[row][wave][0] = rs;
                part[row][wave][1] = rq;
            }
        }
    }
    __syncthreads();
    if (tid < 128) {
        int row = tid >> 1, j = tid & 1;
        tot[row][j] = part[row][0][j] + part[row][1][j] + part[row][2][j] + part[row][3][j];
    }
    __syncthreads();

    float meanv[4][4], rstdv[4][4];
    #pragma unroll
    for (int mt = 0; mt < 4; ++mt)
        #pragma unroll
        for (int r = 0; r < 4; ++r) {
            int row = mt * 16 + q * 4 + r;
            float m = tot[row][0] * (1.0f / D_);
            float var = tot[row][1] * (1.0f / D_) - m * m;
            meanv[mt][r] = m;
            rstdv[mt][r] = rsqrtf((var > 0.0f ? var : 0.0f) + 1e-5f);
        }

    float cs[8], cq[8];
    #pragma unroll
    for (int nt = 0; nt < 8; ++nt) { cs[nt] = 0.f; cq[nt] = 0.f; }
    #pragma unroll
    for (int mt = 0; mt < 4; ++mt) {
        #pragma unroll
        for (int r = 0; r < 4; ++r) {
            int row = mt * 16 + q * 4 + r;
            float mk = mrow[row];
            float m = meanv[mt][r], rs = rstdv[mt][r];
            #pragma unroll
            for (int nt = 0; nt < 8; ++nt) {
                int col = nbase + nt * 16 + m16;
                float xn = ((acc2[mt][nt][r] - m) * rs * ln_g[col] + ln_b[col]) * mk;
                cs[nt] += xn;
                cq[nt] += xn * xn;
            }
        }
    }
    #pragma unroll
    for (int nt = 0; nt < 8; ++nt) {
        cs[nt] += __shfl_xor(cs[nt], 16);  cq[nt] += __shfl_xor(cq[nt], 16);
        cs[nt] += __shfl_xor(cs[nt], 32);  cq[nt] += __shfl_xor(cq[nt], 32);
    }
    if (lane < 16) {
        #pragma unroll
        for (int nt = 0; nt < 8; ++nt) {
            int col = nbase + nt * 16 + m16;
            colsum[col][0] = cs[nt];
            colsum[col][1] = cq[nt];
        }
    }
    __syncthreads();
    for (int i = tid; i < 512; i += 256) {
        atomicAdd(&psum[(size_t)b * D_ + i], colsum[i][0]);
        atomicAdd(&psumsq[(size_t)b * D_ + i], colsum[i][1]);
    }
}

// ---------------------------------------------------------------------------
// Kernel 4: per-batch MLP head: mean/std -> p1/gelu -> p2/tanh, coeff_norm
// ---------------------------------------------------------------------------
__global__ __launch_bounds__(512) void mlp_kernel(
    const float* __restrict__ psum, const float* __restrict__ psumsq,
    const float* __restrict__ sup_ws,
    const float* __restrict__ p1w, const float* __restrict__ p1b,
    const float* __restrict__ p2w, const float* __restrict__ p2b,
    float* __restrict__ out)
{
    int b = blockIdx.x;
    int d = threadIdx.x;
    __shared__ float h[2 * D_];
    __shared__ float s1[D_];
    __shared__ float red[512];

    float n = sup_ws[b];
    float denom = (n > 1.0f) ? n : 1.0f;
    float S = psum[(size_t)b * D_ + d];
    float Q = psumsq[(size_t)b * D_ + d];
    float mean = S / denom;
    float msum = Q - 2.0f * mean * S + n * mean * mean;
    float arg = msum / denom + 1e-6f;
    float sd = sqrtf((arg > 0.0f) ? arg : 0.0f);
    h[d] = mean;
    h[D_ + d] = sd;
    __syncthreads();

    float z = p1b[d];
    const float4* w4 = (const float4*)(p1w + (size_t)d * (2 * D_));
    for (int jj = 0; jj < 2 * D_ / 4; ++jj) {
        float4 wv = w4[jj];
        z += h[jj * 4 + 0] * wv.x + h[jj * 4 + 1] * wv.y
           + h[jj * 4 + 2] * wv.z + h[jj * 4 + 3] * wv.w;
    }
    s1[d] = gelu_exact(z);
    __syncthreads();

    float z2 = p2b[d];
    const float4* w24 = (const float4*)(p2w + (size_t)d * D_);
    for (int jj = 0; jj < D_ / 4; ++jj) {
        float4 wv = w24[jj];
        z2 += s1[jj * 4 + 0] * wv.x + s1[jj * 4 + 1] * wv.y
            + s1[jj * 4 + 2] * wv.z + s1[jj * 4 + 3] * wv.w;
    }
    float st = tanhf(z2);
    if (!(n > 0.0f)) st = 0.0f;
    out[OFF1 + (size_t)b * D_ + d] = st;

    red[d] = st * st;
    __syncthreads();
    for (int s = 256; s > 0; s >>= 1) {
        if (d < s) red[d] += red[d + s];
        __syncthreads();
    }
    if (d == 0) out[OFF10 + b] = sqrtf(red[0]);
}

// ---------------------------------------------------------------------------
extern "C" void kernel_launch(void* const* d_in, const int* in_sizes, int n_in,
                              void* d_out, int out_size, void* d_ws, size_t ws_size,
                              hipStream_t stream) {
    (void)in_sizes; (void)n_in; (void)out_size; (void)ws_size;
    const int*   unit_ids = (const int*)d_in[0];
    const float* dur      = (const float*)d_in[1];
    const float* mask     = (const float*)d_in[2];
    const float* emb      = (const float*)d_in[3];
    const float* aux_w    = (const float*)d_in[4];
    const float* aux_b    = (const float*)d_in[5];
    const float* conv1_w  = (const float*)d_in[6];
    const float* conv1_b  = (const float*)d_in[7];
    const float* conv2_w  = (const float*)d_in[8];
    const float* conv2_b  = (const float*)d_in[9];
    const float* ln_g     = (const float*)d_in[10];
    const float* ln_b     = (const float*)d_in[11];
    const float* p1_w     = (const float*)d_in[12];
    const float* p1_b     = (const float*)d_in[13];
    const float* p2_w     = (const float*)d_in[14];
    const float* p2_b     = (const float*)d_in[15];
    float* out = (float*)d_out;

    char* ws = (char*)d_ws;
    float*          rr     = (float*)(ws + WS_RR);
    float*          sup    = (float*)(ws + WS_SUP);
    float*          psum   = (float*)(ws + WS_PSUM);
    float*          psumsq = (float*)(ws + WS_PSUMSQ);
    __hip_bfloat16* W1p    = (__hip_bfloat16*)(ws + WS_W1P);
    unsigned char*  W2p    = (unsigned char*)(ws + WS_W2P);

    prepack_kernel<<<dim3(384), dim3(256), 0, stream>>>(
        conv1_w, conv2_w, W1p, W2p, psum);
    stats_kernel<<<dim3(B_), dim3(256), 0, stream>>>(dur, mask, rr, sup, out);
    fused_conv_kernel<<<dim3(T_ / 64, B_), dim3(256), 0, stream>>>(
        unit_ids, rr, emb, aux_w, aux_b, W1p, conv1_b, W2p, conv2_b,
        ln_g, ln_b, mask, psum, psumsq);
    mlp_kernel<<<dim3(B_), dim3(512), 0, stream>>>(
        psum, psumsq, sup, p1_w, p1_b, p2_w, p2_b, out);
}

// Round 5
// 572.820 us; speedup vs baseline: 1.3593x; 1.3593x over previous
//
#include <hip/hip_runtime.h>
#include <hip/hip_bf16.h>
#include <math.h>

#define B_  32
#define T_  2048
#define D_  512
#define V_  1024
#define K_  3

typedef __attribute__((ext_vector_type(8))) short   short8;
typedef __attribute__((ext_vector_type(4))) float   floatx4;

#define SCALE_A 64.0f          // activation fp8 scale (conv2 input)
#define SCALE_W 16.0f          // weight fp8 scale
#define INV_SCALES (1.0f/(SCALE_A*SCALE_W))

// ---- output flat offsets (elements, fp32) ----
#define OFF0 0        // global_rate      [32]
#define OFF1 32       // summary_state    [32*512]
#define OFF2 16416    // residual_mean    [32]
#define OFF3 16448    // residual_var     [32]
#define OFF4 16480    // coverage         [32]
#define OFF5 16512    // mask             [32*2048]
#define OFF6 82048    // logdur           [32*2048]
#define OFF7 147584   // ref_residual     [32*2048]
#define OFF8 213120   // attn             [32*2048]
#define OFF9 278656   // prompt_role_fit  [32*2048]
#define OFF10 344192  // coeff_norm       [32]

// ---- workspace byte offsets ----
#define WS_RR     0          // fp32 [32][2048]              262144 B
#define WS_SUP    262144     // fp32 [32]                       128 B
#define WS_PSUM   262272     // fp32 [32][512]                65536 B
#define WS_PSUMSQ 327808     // fp32 [32][512]                65536 B
#define WS_W1P    393344     // bf16 frag-packed conv1 w    1572864 B
#define WS_W2P    1966208    // fp8  frag-packed conv2 w     786432 B
#define WS_H1BUF  2752640    // fp8 [32][2050][512]        33587200 B (split path only)
#define WS_SPLIT_NEED (WS_H1BUF + 33587200ull)   // 36,339,840 B

__device__ __forceinline__ __hip_bfloat16 f2bf(float x) { return __float2bfloat16(x); }
__device__ __forceinline__ float gelu_exact(float v) {
    return 0.5f * v * (1.0f + erff(v * 0.70710678118654752440f));
}
__device__ __forceinline__ unsigned char f2fp8(float x) {
    int v = __builtin_amdgcn_cvt_pk_fp8_f32(x, x, 0, false);
    return (unsigned char)(v & 0xFF);
}
__device__ __forceinline__ float clampf(float v, float lo, float hi) {
    v = (v > lo) ? v : lo;
    return (v < hi) ? v : hi;
}

__device__ __forceinline__ float block_reduce_sum(float v, float* red, int tid) {
    __syncthreads();
    red[tid] = v;
    __syncthreads();
    for (int s = 128; s > 0; s >>= 1) {
        if (tid < s) red[tid] += red[tid + s];
        __syncthreads();
    }
    float r = red[0];
    __syncthreads();
    return r;
}

// ---------------------------------------------------------------------------
// Kernel 1: prepack weights into MFMA-fragment-linear layouts; zero psum and
//   (split path) H1buf causal pad rows.
//  Layout: idx = (((k*16+ci)*32+ntg)*64+lane)*8+e = w[col][kin][k],
//    col = ntg*16 + (lane&15), kin = ci*32 + (lane>>4)*8 + e
// ---------------------------------------------------------------------------
__global__ __launch_bounds__(256) void prepack_kernel(
    const float* __restrict__ w1, const float* __restrict__ w2,
    __hip_bfloat16* __restrict__ W1p, unsigned char* __restrict__ W2p,
    float* __restrict__ psum, unsigned char* __restrict__ h1pad)
{
    int pid = blockIdx.x * 256 + threadIdx.x;   // 0 .. 98303
    int lane = pid & 63;
    int n = lane & 15, q = lane >> 4;
    int ntg = (pid >> 6) & 31;
    int ci  = (pid >> 11) & 15;
    int k   = pid >> 15;                        // 0..2
    int col = ntg * 16 + n;
    int kin = ci * 32 + q * 8;

    short8 wv1;
    unsigned char wv2[8];
    #pragma unroll
    for (int e = 0; e < 8; ++e) {
        size_t src = ((size_t)col * D_ + kin + e) * K_ + k;
        union { __hip_bfloat16 b; short s; } u;
        u.b = f2bf(w1[src]);
        wv1[e] = u.s;
        wv2[e] = f2fp8(w2[src] * SCALE_W);
    }
    *(short8*)(W1p + (size_t)pid * 8) = wv1;
    *(double*)(W2p + (size_t)pid * 8) = *(double*)wv2;

    if (pid < 32768) psum[pid] = 0.0f;          // psum + psumsq contiguous
    if (h1pad != nullptr && pid < 32768) {      // zero 2 causal pad rows/batch
        int b = pid >> 10;
        int r = (pid >> 9) & 1;
        int d = pid & 511;
        h1pad[((size_t)b * 2050 + r) * 512 + d] = 0;
    }
}

// ---------------------------------------------------------------------------
// Kernel 2: per-batch stats (median via LDS bitonic sort) + T-wise outputs
// ---------------------------------------------------------------------------
__global__ __launch_bounds__(256) void stats_kernel(
    const float* __restrict__ dur, const float* __restrict__ maskp,
    float* __restrict__ rr_ws, float* __restrict__ sup_ws,
    float* __restrict__ out)
{
    int b = blockIdx.x;
    int tid = threadIdx.x;
    __shared__ float sv[T_];
    __shared__ float red[256];
    __shared__ float nsh;

    const float* durb = dur + (size_t)b * T_;
    const float* mkb  = maskp + (size_t)b * T_;

    float ld[8], mk[8];
    float cnt = 0.0f;
    #pragma unroll
    for (int i = 0; i < 8; ++i) {
        int t = tid + i * 256;
        float m = clampf(mkb[t], 0.0f, 1.0f);
        float dv = durb[t];
        dv = (dv >= 1e-4f) ? dv : 1e-4f;
        float l = logf(dv) * m;
        ld[i] = l; mk[i] = m;
        bool valid = m > 0.5f;
        cnt += valid ? 1.0f : 0.0f;
        sv[t] = valid ? l : 1e30f;
    }
    float n = block_reduce_sum(cnt, red, tid);
    if (tid == 0) nsh = n;

    for (int k = 2; k <= T_; k <<= 1) {
        for (int j = k >> 1; j > 0; j >>= 1) {
            __syncthreads();
            #pragma unroll
            for (int s = 0; s < 8; ++s) {
                int i = tid + s * 256;
                int ixj = i ^ j;
                if (ixj > i) {
                    float a = sv[i], c = sv[ixj];
                    bool up = ((i & k) == 0);
                    if ((a > c) == up) { sv[i] = c; sv[ixj] = a; }
                }
            }
        }
    }
    __syncthreads();
    n = nsh;
    float med = 0.0f;
    if (n > 0.5f) {
        int ni = (int)(n + 0.5f);
        med = sv[(ni - 1) >> 1];    // torch-style lower median
    }
    med = clampf(med, -20.0f, 20.0f);

    float denom = (n > 1.0f) ? n : 1.0f;
    float rv[8];
    float ssum = 0.0f;
    #pragma unroll
    for (int i = 0; i < 8; ++i) { rv[i] = (ld[i] - med) * mk[i]; ssum += rv[i]; }
    float rsum = block_reduce_sum(ssum, red, tid);
    float rm = clampf(rsum / denom, -40.0f, 40.0f);

    float vsum_l = 0.0f;
    #pragma unroll
    for (int i = 0; i < 8; ++i) { float dd = rv[i] - rm; vsum_l += dd * dd * mk[i]; }
    float vsum = block_reduce_sum(vsum_l, red, tid);
    float var = clampf(vsum / denom, 1e-4f, 1e4f);

    float inv_sup = 1.0f / denom;
    #pragma unroll
    for (int i = 0; i < 8; ++i) {
        int t = tid + i * 256;
        size_t o = (size_t)b * T_ + t;
        out[OFF5 + o] = mk[i];
        out[OFF6 + o] = ld[i];
        out[OFF7 + o] = rv[i];
        out[OFF8 + o] = mk[i] * inv_sup;
        out[OFF9 + o] = rm * mk[i];
        rr_ws[o] = rv[i];
    }
    if (tid == 0) {
        out[OFF0 + b] = med;
        out[OFF2 + b] = rm;
        out[OFF3 + b] = var;
        float cov = n * (1.0f / (float)T_);
        out[OFF4 + b] = (cov > 0.05f) ? cov : 0.05f;
        sup_ws[b] = n;
    }
}

// ===========================================================================
// SPLIT PATH (used when ws_size >= 36.4 MB)
// ===========================================================================
// Kernel S1: conv1 gather-GEMM, 128x128 tile, 4 waves (2x2 of 64x64),
//   double-buffered A-staging (1 barrier/K-chunk), gelu -> fp8*64 -> H1buf.
// ---------------------------------------------------------------------------
#define S1LD 40   // H0 row stride (bf16 elems): 32 + 8
__global__ __launch_bounds__(256, 1) void conv1_split_kernel(
    const int* __restrict__ ids, const float* __restrict__ rr,
    const float* __restrict__ emb,
    const float* __restrict__ aux_w, const float* __restrict__ aux_b,
    const __hip_bfloat16* __restrict__ W1p, const float* __restrict__ bias1,
    unsigned char* __restrict__ H1buf)
{
    __shared__ int   lid[132];
    __shared__ float lrr[132];
    __shared__ __align__(16) __hip_bfloat16 H0[2][132 * S1LD];

    int tt  = blockIdx.x;           // 0..15  t1-tile
    int nt0 = blockIdx.y;           // 0..3
    int b   = blockIdx.z;           // 0..31
    int r0  = tt << 7;              // conv1 output rows r0..r0+127 (t1 space)
    int n0g = nt0 << 3;             // base 16-col group (n0 = nt0*128)
    int tid = threadIdx.x;
    int wave = tid >> 6, lane = tid & 63;
    int wm = wave & 1, wn = wave >> 1;
    int q = lane >> 4, m16 = lane & 15;

    if (tid < 130) {
        int t0 = r0 - 2 + tid;      // H0 row j <-> hidden t0 = r0-2+j
        bool v = (t0 >= 0);
        lid[tid] = v ? ids[b * T_ + t0] : -1;
        lrr[tid] = v ? rr[(size_t)b * T_ + t0] : 0.0f;
    }
    __syncthreads();

    floatx4 acc[4][4];
    #pragma unroll
    for (int i = 0; i < 4; ++i)
        #pragma unroll
        for (int j = 0; j < 4; ++j)
            acc[i][j] = (floatx4){0.f, 0.f, 0.f, 0.f};

    // stage chunk ci of H0 into buffer sel (130 rows x 32 cols)
    #define STAGE_H0(ci, sel)                                                  \
    for (int g = tid; g < 130 * 8; g += 256) {                                 \
        int row = g >> 3, c4 = g & 7;                                          \
        int id = lid[row];                                                     \
        float vr = lrr[row];                                                   \
        float zf = (id < 0) ? 0.0f : 1.0f;                                     \
        int idc = (id < 0) ? 0 : id;                                           \
        float4 ev = *(const float4*)(emb + (size_t)idc * D_ + (ci) * 32 + c4 * 4); \
        float4 aw = *(const float4*)(aux_w + (ci) * 32 + c4 * 4);              \
        float4 ab = *(const float4*)(aux_b + (ci) * 32 + c4 * 4);              \
        short hv[4];                                                           \
        union { __hip_bfloat16 bb; short ss; } u;                              \
        u.bb = f2bf((ev.x + vr * aw.x + ab.x) * zf); hv[0] = u.ss;             \
        u.bb = f2bf((ev.y + vr * aw.y + ab.y) * zf); hv[1] = u.ss;             \
        u.bb = f2bf((ev.z + vr * aw.z + ab.z) * zf); hv[2] = u.ss;             \
        u.bb = f2bf((ev.w + vr * aw.w + ab.w) * zf); hv[3] = u.ss;             \
        *(double*)(&H0[sel][row * S1LD + c4 * 4]) = *(double*)hv;              \
    }

    STAGE_H0(0, 0)
    __syncthreads();

    for (int ci = 0; ci < 16; ++ci) {
        int sel = ci & 1;
        if (ci + 1 < 16) { STAGE_H0(ci + 1, sel ^ 1) }   // prefetch next chunk
        #pragma unroll
        for (int k1 = 0; k1 < 3; ++k1) {
            short8 bfr[4];
            #pragma unroll
            for (int nt = 0; nt < 4; ++nt) {
                int ntg = n0g + wn * 4 + nt;
                bfr[nt] = *(const short8*)(W1p +
                    ((size_t)((k1 * 16 + ci) * 32 + ntg) * 64 + lane) * 8);
            }
            #pragma unroll
            for (int mt = 0; mt < 4; ++mt) {
                short8 afr = *(const short8*)(&H0[sel][(wm * 64 + mt * 16 + m16 + k1) * S1LD + q * 8]);
                #pragma unroll
                for (int nt = 0; nt < 4; ++nt)
                    acc[mt][nt] = __builtin_amdgcn_mfma_f32_16x16x32_bf16(
                        afr, bfr[nt], acc[mt][nt], 0, 0, 0);
            }
        }
        __syncthreads();   // sel reads done; sel^1 writes done
    }

    // epilogue: gelu(acc+bias1)*SCALE_A -> fp8 -> H1buf[b][2+r0+row][n0+col]
    unsigned char* Ob = H1buf + ((size_t)b * 2050 + 2 + r0) * 512 + (n0g << 4);
    #pragma unroll
    for (int mt = 0; mt < 4; ++mt) {
        #pragma unroll
        for (int nt = 0; nt < 4; ++nt) {
            int col = wn * 64 + nt * 16 + m16;
            float bsv = bias1[(n0g << 4) + col];
            #pragma unroll
            for (int r = 0; r < 4; ++r) {
                int row = wm * 64 + mt * 16 + q * 4 + r;
                float v = gelu_exact(acc[mt][nt][r] + bsv) * SCALE_A;
                Ob[(size_t)row * 512 + col] = f2fp8(v);
            }
        }
    }
    #undef STAGE_H0
}

// ---------------------------------------------------------------------------
// Kernel S2: conv2 (fp8 MFMA) + gelu + LN + masked column sums.
//   BM=64 x BN=512 per block; A-tile (66 rows) staged ONCE from H1buf, then a
//   48-step barrier-free K-loop streaming frag-packed weights.
// ---------------------------------------------------------------------------
#define H1S 520
__global__ __launch_bounds__(256, 1) void conv2ln_kernel(
    const unsigned char* __restrict__ H1buf, const unsigned char* __restrict__ W2p,
    const float* __restrict__ bias2,
    const float* __restrict__ ln_g, const float* __restrict__ ln_b,
    const float* __restrict__ maskp,
    float* __restrict__ psum, float* __restrict__ psumsq)
{
    __shared__ __align__(16) unsigned char H1s[66 * H1S];   // 34320 B
    __shared__ float mrow[64];
    __shared__ float part[64][4][2];
    __shared__ float tot[64][2];
    __shared__ float colsum[512][2];

    int tile = blockIdx.x;          // 0..31
    int b    = blockIdx.y;          // 0..31
    int r0   = tile << 6;           // output rows r0..r0+63
    int tid  = threadIdx.x;
    int wave = tid >> 6, lane = tid & 63;
    int q = lane >> 4, m16 = lane & 15;
    int nbase = wave << 7;          // 128-col slice per wave

    // stage A: padded rows r0..r0+65 (coalesced 16B loads)
    const unsigned char* src = H1buf + ((size_t)b * 2050 + r0) * 512;
    for (int g = tid; g < 66 * 32; g += 256) {
        int row = g >> 5, h = g & 31;
        *(float4*)(&H1s[row * H1S + h * 16]) = *(const float4*)(src + (size_t)row * 512 + h * 16);
    }
    if (tid < 64)
        mrow[tid] = clampf(maskp[(size_t)b * T_ + r0 + tid], 0.0f, 1.0f);
    __syncthreads();

    floatx4 acc2[4][8];
    #pragma unroll
    for (int i = 0; i < 4; ++i)
        #pragma unroll
        for (int j = 0; j < 8; ++j)
            acc2[i][j] = (floatx4){0.f, 0.f, 0.f, 0.f};

    for (int s = 0; s < 48; ++s) {
        int k2 = s >> 4, ci = s & 15;
        long bfr2[8];
        #pragma unroll
        for (int nt = 0; nt < 8; ++nt) {
            int ntg = wave * 8 + nt;
            bfr2[nt] = *(const long*)(W2p +
                ((size_t)((k2 * 16 + ci) * 32 + ntg) * 64 + lane) * 8);
        }
        #pragma unroll
        for (int mt = 0; mt < 4; ++mt) {
            long afr2 = *(const long*)(&H1s[(mt * 16 + m16 + k2) * H1S + ci * 32 + q * 8]);
            #pragma unroll
            for (int nt = 0; nt < 8; ++nt)
                acc2[mt][nt] = __builtin_amdgcn_mfma_f32_16x16x32_fp8_fp8(
                    afr2, bfr2[nt], acc2[mt][nt], 0, 0, 0);
        }
    }

    // gelu + LN + masked column sums
    #pragma unroll
    for (int mt = 0; mt < 4; ++mt)
        #pragma unroll
        for (int nt = 0; nt < 8; ++nt) {
            int col = nbase + nt * 16 + m16;
            float bsv = bias2[col];
            #pragma unroll
            for (int r = 0; r < 4; ++r)
                acc2[mt][nt][r] = gelu_exact(acc2[mt][nt][r] * INV_SCALES + bsv);
        }

    #pragma unroll
    for (int mt = 0; mt < 4; ++mt) {
        #pragma unroll
        for (int r = 0; r < 4; ++r) {
            float rs = 0.f, rq = 0.f;
            #pragma unroll
            for (int nt = 0; nt < 8; ++nt) {
                float v = acc2[mt][nt][r];
                rs += v; rq += v * v;
            }
            rs += __shfl_xor(rs, 1);  rq += __shfl_xor(rq, 1);
            rs += __shfl_xor(rs, 2);  rq += __shfl_xor(rq, 2);
            rs += __shfl_xor(rs, 4);  rq += __shfl_xor(rq, 4);
            rs += __shfl_xor(rs, 8);  rq += __shfl_xor(rq, 8);
            if (m16 == 0) {
                int row = mt * 16 + q * 4 + r;
                part[row][wave][0] = rs;
                part[row][wave][1] = rq;
            }
        }
    }
    __syncthreads();
    if (tid < 128) {
        int row = tid >> 1, j = tid & 1;
        tot[row][j] = part[row][0][j] + part[row][1][j] + part[row][2][j] + part[row][3][j];
    }
    __syncthreads();

    float meanv[4][4], rstdv[4][4];
    #pragma unroll
    for (int mt = 0; mt < 4; ++mt)
        #pragma unroll
        for (int r = 0; r < 4; ++r) {
            int row = mt * 16 + q * 4 + r;
            float m = tot[row][0] * (1.0f / D_);
            float var = tot[row][1] * (1.0f / D_) - m * m;
            meanv[mt][r] = m;
            rstdv[mt][r] = rsqrtf((var > 0.0f ? var : 0.0f) + 1e-5f);
        }

    float cs[8], cq[8];
    #pragma unroll
    for (int nt = 0; nt < 8; ++nt) { cs[nt] = 0.f; cq[nt] = 0.f; }
    #pragma unroll
    for (int mt = 0; mt < 4; ++mt) {
        #pragma unroll
        for (int r = 0; r < 4; ++r) {
            int row = mt * 16 + q * 4 + r;
            float mk = mrow[row];
            float m = meanv[mt][r], rs = rstdv[mt][r];
            #pragma unroll
            for (int nt = 0; nt < 8; ++nt) {
                int col = nbase + nt * 16 + m16;
                float xn = ((acc2[mt][nt][r] - m) * rs * ln_g[col] + ln_b[col]) * mk;
                cs[nt] += xn;
                cq[nt] += xn * xn;
            }
        }
    }
    #pragma unroll
    for (int nt = 0; nt < 8; ++nt) {
        cs[nt] += __shfl_xor(cs[nt], 16);  cq[nt] += __shfl_xor(cq[nt], 16);
        cs[nt] += __shfl_xor(cs[nt], 32);  cq[nt] += __shfl_xor(cq[nt], 32);
    }
    if (lane < 16) {
        #pragma unroll
        for (int nt = 0; nt < 8; ++nt) {
            int col = nbase + nt * 16 + m16;
            colsum[col][0] = cs[nt];
            colsum[col][1] = cq[nt];
        }
    }
    __syncthreads();
    for (int i = tid; i < 512; i += 256) {
        atomicAdd(&psum[(size_t)b * D_ + i], colsum[i][0]);
        atomicAdd(&psumsq[(size_t)b * D_ + i], colsum[i][1]);
    }
}

// ===========================================================================
// FUSED FALLBACK PATH (used when ws_size < 36.4 MB) — unchanged from round 4
// ===========================================================================
#define NR0 84
#define C1T 5
#define H1R 68

__global__ __launch_bounds__(256, 1) void fused_conv_kernel(
    const int* __restrict__ ids, const float* __restrict__ rr,
    const float* __restrict__ emb,
    const float* __restrict__ aux_w, const float* __restrict__ aux_b,
    const __hip_bfloat16* __restrict__ W1p, const float* __restrict__ bias1,
    const unsigned char* __restrict__ W2p, const float* __restrict__ bias2,
    const float* __restrict__ ln_g, const float* __restrict__ ln_b,
    const float* __restrict__ maskp,
    float* __restrict__ psum, float* __restrict__ psumsq)
{
    __shared__ int   lid[NR0];
    __shared__ float lrr[NR0];
    __shared__ __align__(16) __hip_bfloat16 H0[NR0 * 40];
    __shared__ __align__(16) unsigned char H1[H1R * H1S];
    __shared__ float mrow[64];
    __shared__ float part[64][4][2];
    __shared__ float tot[64][2];
    __shared__ float colsum[512][2];

    int tile = blockIdx.x;
    int b    = blockIdx.y;
    int r0   = tile << 6;
    int tid  = threadIdx.x;
    int wave = tid >> 6, lane = tid & 63;
    int q = lane >> 4, m16 = lane & 15;
    int nbase = wave << 7;

    if (tid < NR0) {
        int t = r0 - 4 + tid;
        bool v = (t >= 0) && (t < T_);
        lid[tid] = v ? ids[b * T_ + t] : -1;
        lrr[tid] = v ? rr[(size_t)b * T_ + t] : 0.0f;
    }
    if (tid < 64)
        mrow[tid] = clampf(maskp[(size_t)b * T_ + r0 + tid], 0.0f, 1.0f);

    floatx4 acc1[C1T][8];
    #pragma unroll
    for (int i = 0; i < C1T; ++i)
        #pragma unroll
        for (int j = 0; j < 8; ++j)
            acc1[i][j] = (floatx4){0.f, 0.f, 0.f, 0.f};

    for (int ci = 0; ci < 16; ++ci) {
        __syncthreads();
        for (int g = tid; g < NR0 * 8; g += 256) {
            int row = g >> 3, c4 = g & 7;
            int id = lid[row];
            float vr = lrr[row];
            float zf = (id < 0) ? 0.0f : 1.0f;
            int idc = (id < 0) ? 0 : id;
            float4 ev = *(const float4*)(emb + (size_t)idc * D_ + ci * 32 + c4 * 4);
            float4 aw = *(const float4*)(aux_w + ci * 32 + c4 * 4);
            float4 ab = *(const float4*)(aux_b + ci * 32 + c4 * 4);
            short hv[4];
            union { __hip_bfloat16 bb; short ss; } u;
            u.bb = f2bf((ev.x + vr * aw.x + ab.x) * zf); hv[0] = u.ss;
            u.bb = f2bf((ev.y + vr * aw.y + ab.y) * zf); hv[1] = u.ss;
            u.bb = f2bf((ev.z + vr * aw.z + ab.z) * zf); hv[2] = u.ss;
            u.bb = f2bf((ev.w + vr * aw.w + ab.w) * zf); hv[3] = u.ss;
            *(double*)(&H0[row * 40 + c4 * 4]) = *(double*)hv;
        }
        __syncthreads();
        #pragma unroll
        for (int k1 = 0; k1 < 3; ++k1) {
            short8 bfr[8];
            #pragma unroll
            for (int nt = 0; nt < 8; ++nt) {
                int ntg = wave * 8 + nt;
                bfr[nt] = *(const short8*)(W1p +
                    ((size_t)((k1 * 16 + ci) * 32 + ntg) * 64 + lane) * 8);
            }
            #pragma unroll
            for (int mt = 0; mt < C1T; ++mt) {
                short8 afr = *(const short8*)(&H0[(mt * 16 + m16 + k1) * 40 + q * 8]);
                #pragma unroll
                for (int nt = 0; nt < 8; ++nt)
                    acc1[mt][nt] = __builtin_amdgcn_mfma_f32_16x16x32_bf16(
                        afr, bfr[nt], acc1[mt][nt], 0, 0, 0);
            }
        }
    }
    __syncthreads();

    #pragma unroll
    for (int mt = 0; mt < C1T; ++mt) {
        #pragma unroll
        for (int nt = 0; nt < 8; ++nt) {
            int col = nbase + nt * 16 + m16;
            float bsv = bias1[col];
            #pragma unroll
            for (int r = 0; r < 4; ++r) {
                int j = mt * 16 + q * 4 + r;
                if (j < 66) {
                    float val = gelu_exact(acc1[mt][nt][r] + bsv) * SCALE_A;
                    if (r0 - 2 + j < 0) val = 0.0f;
                    H1[j * H1S + col] = f2fp8(val);
                }
            }
        }
    }
    __syncthreads();

    floatx4 acc2[4][8];
    #pragma unroll
    for (int i = 0; i < 4; ++i)
        #pragma unroll
        for (int j = 0; j < 8; ++j)
            acc2[i][j] = (floatx4){0.f, 0.f, 0.f, 0.f};

    for (int s = 0; s < 48; ++s) {
        int k2 = s >> 4, ci = s & 15;
        long bfr2[8];
        #pragma unroll
        for (int nt = 0; nt < 8; ++nt) {
            int ntg = wave * 8 + nt;
            bfr2[nt] = *(const long*)(W2p +
                ((size_t)((k2 * 16 + ci) * 32 + ntg) * 64 + lane) * 8);
        }
        #pragma unroll
        for (int mt = 0; mt < 4; ++mt) {
            long afr2 = *(const long*)(&H1[(mt * 16 + m16 + k2) * H1S + ci * 32 + q * 8]);
            #pragma unroll
            for (int nt = 0; nt < 8; ++nt)
                acc2[mt][nt] = __builtin_amdgcn_mfma_f32_16x16x32_fp8_fp8(
                    afr2, bfr2[nt], acc2[mt][nt], 0, 0, 0);
        }
    }

    #pragma unroll
    for (int mt = 0; mt < 4; ++mt)
        #pragma unroll
        for (int nt = 0; nt < 8; ++nt) {
            int col = nbase + nt * 16 + m16;
            float bsv = bias2[col];
            #pragma unroll
            for (int r = 0; r < 4; ++r)
                acc2[mt][nt][r] = gelu_exact(acc2[mt][nt][r] * INV_SCALES + bsv);
        }

    #pragma unroll
    for (int mt = 0; mt < 4; ++mt) {
        #pragma unroll
        for (int r = 0; r < 4; ++r) {
            float rs = 0.f, rq = 0.f;
            #pragma unroll
            for (int nt = 0; nt < 8; ++nt) {
                float v = acc2[mt][nt][r];
                rs += v; rq += v * v;
            }
            rs += __shfl_xor(rs, 1);  rq += __shfl_xor(rq, 1);
            rs += __shfl_xor(rs, 2);  rq += __shfl_xor(rq, 2);
            rs += __shfl_xor(rs, 4);  rq += __shfl_xor(rq, 4);
            rs += __shfl_xor(rs, 8);  rq += __shfl_xor(rq, 8);
            if (m16 == 0) {
                int row = mt * 16 + q * 4 + r;
                part[row][wave][0] = rs;
                part[row][wave][1] = rq;
            }
        }
    }
    __syncthreads();
    if (tid < 128) {
        int row = tid >> 1, j = tid & 1;
        tot[row][j] = part[row][0][j] + part[row][1][j] + part[row][2][j] + part[row][3][j];
    }
    __syncthreads();

    float meanv[4][4], rstdv[4][4];
    #pragma unroll
    for (int mt = 0; mt < 4; ++mt)
        #pragma unroll
        for (int r = 0; r < 4; ++r) {
            int row = mt * 16 + q * 4 + r;
            float m = tot[row][0] * (1.0f / D_);
            float var = tot[row][1] * (1.0f / D_) - m * m;
            meanv[mt][r] = m;
            rstdv[mt][r] = rsqrtf((var > 0.0f ? var : 0.0f) + 1e-5f);
        }

    float cs[8], cq[8];
    #pragma unroll
    for (int nt = 0; nt < 8; ++nt) { cs[nt] = 0.f; cq[nt] = 0.f; }
    #pragma unroll
    for (int mt = 0; mt < 4; ++mt) {
        #pragma unroll
        for (int r = 0; r < 4; ++r) {
            int row = mt * 16 + q * 4 + r;
            float mk = mrow[row];
            float m = meanv[mt][r], rs = rstdv[mt][r];
            #pragma unroll
            for (int nt = 0; nt < 8; ++nt) {
                int col = nbase + nt * 16 + m16;
                float xn = ((acc2[mt][nt][r] - m) * rs * ln_g[col] + ln_b[col]) * mk;
                cs[nt] += xn;
                cq[nt] += xn * xn;
            }
        }
    }
    #pragma unroll
    for (int nt = 0; nt < 8; ++nt) {
        cs[nt] += __shfl_xor(cs[nt], 16);  cq[nt] += __shfl_xor(cq[nt], 16);
        cs[nt] += __shfl_xor(cs[nt], 32);  cq[nt] += __shfl_xor(cq[nt], 32);
    }
    if (lane < 16) {
        #pragma unroll
        for (int nt = 0; nt < 8; ++nt) {
            int col = nbase + nt * 16 + m16;
            colsum[col][0] = cs[nt];
            colsum[col][1] = cq[nt];
        }
    }
    __syncthreads();
    for (int i = tid; i < 512; i += 256) {
        atomicAdd(&psum[(size_t)b * D_ + i], colsum[i][0]);
        atomicAdd(&psumsq[(size_t)b * D_ + i], colsum[i][1]);
    }
}

// ---------------------------------------------------------------------------
// Kernel: per-batch MLP head: mean/std -> p1/gelu -> p2/tanh, coeff_norm
// ---------------------------------------------------------------------------
__global__ __launch_bounds__(512) void mlp_kernel(
    const float* __restrict__ psum, const float* __restrict__ psumsq,
    const float* __restrict__ sup_ws,
    const float* __restrict__ p1w, const float* __restrict__ p1b,
    const float* __restrict__ p2w, const float* __restrict__ p2b,
    float* __restrict__ out)
{
    int b = blockIdx.x;
    int d = threadIdx.x;
    __shared__ float h[2 * D_];
    __shared__ float s1[D_];
    __shared__ float red[512];

    float n = sup_ws[b];
    float denom = (n > 1.0f) ? n : 1.0f;
    float S = psum[(size_t)b * D_ + d];
    float Q = psumsq[(size_t)b * D_ + d];
    float mean = S / denom;
    float msum = Q - 2.0f * mean * S + n * mean * mean;
    float arg = msum / denom + 1e-6f;
    float sd = sqrtf((arg > 0.0f) ? arg : 0.0f);
    h[d] = mean;
    h[D_ + d] = sd;
    __syncthreads();

    float z = p1b[d];
    const float4* w4 = (const float4*)(p1w + (size_t)d * (2 * D_));
    for (int jj = 0; jj < 2 * D_ / 4; ++jj) {
        float4 wv = w4[jj];
        z += h[jj * 4 + 0] * wv.x + h[jj * 4 + 1] * wv.y
           + h[jj * 4 + 2] * wv.z + h[jj * 4 + 3] * wv.w;
    }
    s1[d] = gelu_exact(z);
    __syncthreads();

    float z2 = p2b[d];
    const float4* w24 = (const float4*)(p2w + (size_t)d * D_);
    for (int jj = 0; jj < D_ / 4; ++jj) {
        float4 wv = w24[jj];
        z2 += s1[jj * 4 + 0] * wv.x + s1[jj * 4 + 1] * wv.y
            + s1[jj * 4 + 2] * wv.z + s1[jj * 4 + 3] * wv.w;
    }
    float st = tanhf(z2);
    if (!(n > 0.0f)) st = 0.0f;
    out[OFF1 + (size_t)b * D_ + d] = st;

    red[d] = st * st;
    __syncthreads();
    for (int s = 256; s > 0; s >>= 1) {
        if (d < s) red[d] += red[d + s];
        __syncthreads();
    }
    if (d == 0) out[OFF10 + b] = sqrtf(red[0]);
}

// ---------------------------------------------------------------------------
extern "C" void kernel_launch(void* const* d_in, const int* in_sizes, int n_in,
                              void* d_out, int out_size, void* d_ws, size_t ws_size,
                              hipStream_t stream) {
    (void)in_sizes; (void)n_in; (void)out_size;
    const int*   unit_ids = (const int*)d_in[0];
    const float* dur      = (const float*)d_in[1];
    const float* mask     = (const float*)d_in[2];
    const float* emb      = (const float*)d_in[3];
    const float* aux_w    = (const float*)d_in[4];
    const float* aux_b    = (const float*)d_in[5];
    const float* conv1_w  = (const float*)d_in[6];
    const float* conv1_b  = (const float*)d_in[7];
    const float* conv2_w  = (const float*)d_in[8];
    const float* conv2_b  = (const float*)d_in[9];
    const float* ln_g     = (const float*)d_in[10];
    const float* ln_b     = (const float*)d_in[11];
    const float* p1_w     = (const float*)d_in[12];
    const float* p1_b     = (const float*)d_in[13];
    const float* p2_w     = (const float*)d_in[14];
    const float* p2_b     = (const float*)d_in[15];
    float* out = (float*)d_out;

    char* ws = (char*)d_ws;
    float*          rr     = (float*)(ws + WS_RR);
    float*          sup    = (float*)(ws + WS_SUP);
    float*          psum   = (float*)(ws + WS_PSUM);
    float*          psumsq = (float*)(ws + WS_PSUMSQ);
    __hip_bfloat16* W1p    = (__hip_bfloat16*)(ws + WS_W1P);
    unsigned char*  W2p    = (unsigned char*)(ws + WS_W2P);
    unsigned char*  H1buf  = (unsigned char*)(ws + WS_H1BUF);

    const bool split = (ws_size >= WS_SPLIT_NEED);   // constant across calls

    prepack_kernel<<<dim3(384), dim3(256), 0, stream>>>(
        conv1_w, conv2_w, W1p, W2p, psum, split ? H1buf : nullptr);
    stats_kernel<<<dim3(B_), dim3(256), 0, stream>>>(dur, mask, rr, sup, out);

    if (split) {
        conv1_split_kernel<<<dim3(16, 4, 32), dim3(256), 0, stream>>>(
            unit_ids, rr, emb, aux_w, aux_b, W1p, conv1_b, H1buf);
        conv2ln_kernel<<<dim3(32, 32), dim3(256), 0, stream>>>(
            H1buf, W2p, conv2_b, ln_g, ln_b, mask, psum, psumsq);
    } else {
        fused_conv_kernel<<<dim3(T_ / 64, B_), dim3(256), 0, stream>>>(
            unit_ids, rr, emb, aux_w, aux_b, W1p, conv1_b, W2p, conv2_b,
            ln_g, ln_b, mask, psum, psumsq);
    }
    mlp_kernel<<<dim3(B_), dim3(512), 0, stream>>>(
        psum, psumsq, sup, p1_w, p1_b, p2_w, p2_b, out);
}